// Round 1
// 525.377 us; speedup vs baseline: 1.1126x; 1.1126x over previous
//
#include <hip/hip_runtime.h>

// ---------------------------------------------------------------------------
// MultiHeadAttention_60000693125780 — round 6
//  = round 5's proven conv_qkv/scores/softmax (untouched; conv_qkv is at the
//    2-barrier-structure MFMA ceiling: 51% of 2075 TF = measured MfmaUtil 49%)
//  + coalesced prep (LDS-transpose kernels; old prep gathered 4B/lane at 1KiB
//    stride = 64 segments/load, scalar 2B stores)
//  + BK=64 for conv_o & pv (both grid-capped at 2 blocks/CU, so 24KB LDS is
//    free; halves barrier/vmcnt(0)-drain count per unit work).
//  All math bit-identical to round 5 (same f2bf, same K-accumulation order)
//  -> absmax must stay exactly 0.03125.
// Layouts: Qh/Ql,Kh/Kl [nn][dd][t] bf16 hi/lo; Vt [nn][t][dd] bf16;
//          Ph [nn][q][k'] bf16; Sp padded NHWC bf16 [4][10][258][512]
// BK=64 LDS swizzle (pitch 64 shorts = 128B):
//   stage call = 8 rows x 8 chunks: lane l -> row l>>3, LDS chunk-pos l&7,
//   global chunk (l&7)^(l>>3); reader chunk-pos = (ks*4+lq)^(row&7)
//   -> 8 lanes per bank-quad per ds_read_b128 (conflict-free).
// ---------------------------------------------------------------------------

typedef __attribute__((ext_vector_type(8))) short short8;
typedef __attribute__((ext_vector_type(4))) float f32x4;
typedef __attribute__((ext_vector_type(4))) short short4v;

#define MFMA16(a, b, c) __builtin_amdgcn_mfma_f32_16x16x32_bf16((a), (b), (c), 0, 0, 0)

__device__ __forceinline__ void gl_lds16(const void* g, void* l) {
    __builtin_amdgcn_global_load_lds(
        (const __attribute__((address_space(1))) unsigned int*)g,
        (__attribute__((address_space(3))) unsigned int*)l, 16, 0, 0);
}
__device__ __forceinline__ unsigned short f2bf(float f) {
    unsigned u = __float_as_uint(f);
    return (unsigned short)((u + 0x7fffu + ((u >> 16) & 1u)) >> 16);
}
__device__ __forceinline__ float bf2f(unsigned short h) {
    return __uint_as_float(((unsigned)h) << 16);
}
__device__ __forceinline__ unsigned int pack_hl(float f) {
    unsigned short h = f2bf(f);
    unsigned short lo = f2bf(f - bf2f(h));
    return (unsigned)h | ((unsigned)lo << 16);
}

// ---- halo zeroing for padded inputs: 84 halo cells per (array, n) ----
__global__ __launch_bounds__(256) void k_zero_halo(
        unsigned short* __restrict__ Xqh, unsigned short* __restrict__ Xql,
        unsigned short* __restrict__ Xkh, unsigned short* __restrict__ Xkl,
        unsigned short* __restrict__ Xvh) {
    const int w = threadIdx.x >> 6, l = threadIdx.x & 63;
    int job = blockIdx.x * 4 + w;            // 13440 jobs = 5 arrays * 32 n * 84
    int a = job / 2688;
    int r = job - a * 2688;
    int n = r / 84;
    int ii = r - n * 84;
    unsigned short* arr = a == 0 ? Xqh : a == 1 ? Xql : a == 2 ? Xkh
                                 : a == 3 ? Xkl : Xvh;
    // halo cells of the 34x10 grid: 0..10, {19,20,29,30,...,319,320}, 329..339
    int cell;
    if (ii < 11)      cell = ii;
    else if (ii < 73) { int j = ii - 11; cell = 19 + (j >> 1) * 10 + (j & 1); }
    else              cell = 329 + (ii - 73);
    short8 z8 = {0, 0, 0, 0, 0, 0, 0, 0};
    *(short8*)&arr[(size_t)(n * 340 + cell) * 512 + l * 8] = z8;
}

// ---- weight prep: [co][ci][tap] fp32 -> [co][tap][ci] bf16 hi(/lo) ----
__global__ __launch_bounds__(256) void k_prep_w(
        const float* __restrict__ Wq, const float* __restrict__ Wk,
        const float* __restrict__ Wv, const float* __restrict__ Wo,
        unsigned short* __restrict__ Wqh, unsigned short* __restrict__ Wql,
        unsigned short* __restrict__ Wkh, unsigned short* __restrict__ Wkl,
        unsigned short* __restrict__ Wvh, unsigned short* __restrict__ Woh) {
    __shared__ __align__(16) unsigned int L[4608];   // [tap][ci] hi|lo<<16
    const int b = blockIdx.x;                        // 2048 = 4z * 512co
    const int co = b & 511, z = b >> 9;
    const float* W = z == 0 ? Wq : z == 1 ? Wk : z == 2 ? Wv : Wo;
    unsigned short* Wh = z == 0 ? Wqh : z == 1 ? Wkh : z == 2 ? Wvh : Woh;
    unsigned short* Wl = z == 0 ? Wql : z == 1 ? Wkl : nullptr;
    const int tid = threadIdx.x;
    const float* Wc = W + co * 4608;
#pragma unroll
    for (int it = 0; it < 9; ++it) {
        int p = it * 256 + tid;                      // pair index 0..2303
        float2 rd = *(const float2*)&Wc[p * 2];
        int e0 = p * 2;
        int ci0 = e0 / 9, t0 = e0 - ci0 * 9;
        L[t0 * 512 + ci0] = pack_hl(rd.x);
        int e1 = e0 + 1;
        int ci1 = e1 / 9, t1 = e1 - ci1 * 9;
        L[t1 * 512 + ci1] = pack_hl(rd.y);
    }
    __syncthreads();
    unsigned short* Whc = Wh + co * 4608;
    unsigned short* Wlc = Wl ? Wl + co * 4608 : nullptr;
#pragma unroll
    for (int it = 0; it < 18; ++it) {
        int j = it * 256 + tid;
        unsigned int u = L[j];
        Whc[j] = (unsigned short)(u & 0xffffu);
        if (Wlc) Wlc[j] = (unsigned short)(u >> 16);
    }
}

// ---- input prep: NCHW fp32 -> padded NHWC bf16 hi(/lo), LDS transpose ----
__global__ __launch_bounds__(256) void k_prep_x(
        const float* __restrict__ q, const float* __restrict__ k,
        const float* __restrict__ v,
        unsigned short* __restrict__ Xqh, unsigned short* __restrict__ Xql,
        unsigned short* __restrict__ Xkh, unsigned short* __restrict__ Xkl,
        unsigned short* __restrict__ Xvh) {
    __shared__ __align__(16) unsigned int T[8192];   // [ci_l 32][pos 256] hi|lo<<16
    const int b = blockIdx.x;                        // 1536 = 3z * 32n * 16cig
    const int cig = b & 15, n = (b >> 4) & 31, z = b >> 9;
    const float* X = z == 0 ? q : z == 1 ? k : v;
    unsigned short* Xh = z == 0 ? Xqh : z == 1 ? Xkh : Xvh;
    unsigned short* Xl = z == 0 ? Xql : z == 1 ? Xkl : nullptr;
    const int tid = threadIdx.x;
    // stage: coalesced float4 reads along pos
#pragma unroll
    for (int it = 0; it < 8; ++it) {
        int ci_l = it * 4 + (tid >> 6);
        int pos = (tid & 63) * 4;
        const float4 rd =
            *(const float4*)&X[(size_t)(n * 512 + cig * 32 + ci_l) * 256 + pos];
        uint4 u;
        u.x = pack_hl(rd.x);
        u.y = pack_hl(rd.y);
        u.z = pack_hl(rd.z);
        u.w = pack_hl(rd.w);
        *(uint4*)&T[ci_l * 256 + pos] = u;           // conflict-free b128 write
    }
    __syncthreads();
    // write: lanes gather 8 ci for one pos, 16B stores
#pragma unroll
    for (int it = 0; it < 4; ++it) {
        int pos = it * 64 + (tid >> 2);
        int ci8 = (tid & 3) * 8;
        short8 h8, l8;
#pragma unroll
        for (int j = 0; j < 8; ++j) {
            unsigned int u = T[(ci8 + j) * 256 + pos];
            h8[j] = (short)(u & 0xffffu);
            l8[j] = (short)(u >> 16);
        }
        int yy = (pos >> 3) + 1, xx = (pos & 7) + 1;
        size_t o = (size_t)((n * 34 + yy) * 10 + xx) * 512 + cig * 32 + ci8;
        *(short8*)&Xh[o] = h8;
        if (Xl) *(short8*)&Xl[o] = l8;
    }
}

// ---- merged QKV conv (16x16): z=0 Q(split), z=1 K(split), z=2 V(->Vt) ----
// UNCHANGED from round 5 (at structural MFMA ceiling for this schedule).
__global__ __launch_bounds__(256) void k_conv_qkv_all(
        const unsigned short* __restrict__ Xqh, const unsigned short* __restrict__ Xql,
        const unsigned short* __restrict__ Xkh, const unsigned short* __restrict__ Xkl,
        const unsigned short* __restrict__ Xvh,
        const unsigned short* __restrict__ Wqh_, const unsigned short* __restrict__ Wql_,
        const unsigned short* __restrict__ Wkh_, const unsigned short* __restrict__ Wkl_,
        const unsigned short* __restrict__ Wvh_,
        const float* __restrict__ bq, const float* __restrict__ bk,
        const float* __restrict__ bv,
        unsigned short* __restrict__ Qh, unsigned short* __restrict__ Ql,
        unsigned short* __restrict__ Kh, unsigned short* __restrict__ Kl,
        unsigned short* __restrict__ Vt) {
    __shared__ __align__(16) short Ah[4096], Al[4096], Bh[4096], Bl[4096];
    const int z = blockIdx.z;
    const bool split = (z < 2);
    const unsigned short* Xh = z == 0 ? Xqh : z == 1 ? Xkh : Xvh;
    const unsigned short* Xl = z == 0 ? Xql : Xkl;
    const unsigned short* Wh = z == 0 ? Wqh_ : z == 1 ? Wkh_ : Wvh_;
    const unsigned short* Wl = z == 0 ? Wql_ : Wkl_;
    const float* bias = z == 0 ? bq : z == 1 ? bk : bv;
    unsigned short* Oh = z == 0 ? Qh : Kh;
    unsigned short* Ol = z == 0 ? Ql : Kl;

    const int tid = threadIdx.x;
    const int w = tid >> 6, l = tid & 63;
    const int n   = blockIdx.x >> 1;
    const int p0  = (blockIdx.x & 1) * 128;
    const int co0 = blockIdx.y * 128;
    const int lm = l & 15, lq = l >> 4;

    int arow[2], brow[2];
#pragma unroll
    for (int i = 0; i < 2; ++i) {
        int rr = w * 32 + i * 16 + (l >> 2);
        int c  = (l & 3) ^ ((rr >> 1) & 3);             // XOR bank swizzle
        int px = p0 + rr;
        int y = px >> 3, x = px & 7;
        arow[i] = ((n * 34 + y + 1) * 10 + (x + 1)) * 512 + c * 8;
        brow[i] = (co0 + rr) * 4608 + c * 8;
    }
    const int lds0 = w * 2048, lds1 = w * 2048 + 1024;

    int aoff[4], boff[4];
#pragma unroll
    for (int mi = 0; mi < 4; ++mi) {
        int row = (w & 1) * 64 + mi * 16 + lm;
        aoff[mi] = row * 32 + (lq ^ ((row >> 1) & 3)) * 8;
    }
#pragma unroll
    for (int ni = 0; ni < 4; ++ni) {
        int row = (w >> 1) * 64 + ni * 16 + lm;
        boff[ni] = row * 32 + (lq ^ ((row >> 1) & 3)) * 8;
    }

    f32x4 acc[4][4];
#pragma unroll
    for (int ni = 0; ni < 4; ++ni) {
        float b = bias[co0 + (w >> 1) * 64 + ni * 16 + lm];
#pragma unroll
        for (int mi = 0; mi < 4; ++mi) acc[mi][ni] = (f32x4){b, b, b, b};
    }

    for (int tap = 0; tap < 9; ++tap) {
        const int tapoff = ((tap / 3 - 1) * 10 + (tap % 3 - 1)) * 512;
        const int wb = tap * 512;
        for (int ci0 = 0; ci0 < 512; ci0 += 32) {
            int a0 = arow[0] + tapoff + ci0, a1 = arow[1] + tapoff + ci0;
            int b0 = brow[0] + wb + ci0,     b1 = brow[1] + wb + ci0;
            gl_lds16(Xh + a0, (char*)Ah + lds0);
            gl_lds16(Xh + a1, (char*)Ah + lds1);
            gl_lds16(Wh + b0, (char*)Bh + lds0);
            gl_lds16(Wh + b1, (char*)Bh + lds1);
            if (split) {
                gl_lds16(Xl + a0, (char*)Al + lds0);
                gl_lds16(Xl + a1, (char*)Al + lds1);
                gl_lds16(Wl + b0, (char*)Bl + lds0);
                gl_lds16(Wl + b1, (char*)Bl + lds1);
            }
            __syncthreads();
            short8 ah[4], bh[4];
#pragma unroll
            for (int mi = 0; mi < 4; ++mi) ah[mi] = *(const short8*)&Ah[aoff[mi]];
#pragma unroll
            for (int ni = 0; ni < 4; ++ni) bh[ni] = *(const short8*)&Bh[boff[ni]];
#pragma unroll
            for (int mi = 0; mi < 4; ++mi)
#pragma unroll
                for (int ni = 0; ni < 4; ++ni)
                    acc[mi][ni] = MFMA16(ah[mi], bh[ni], acc[mi][ni]);
            if (split) {
                short8 alv[4], blv[4];
#pragma unroll
                for (int mi = 0; mi < 4; ++mi) alv[mi] = *(const short8*)&Al[aoff[mi]];
#pragma unroll
                for (int mi = 0; mi < 4; ++mi)
#pragma unroll
                    for (int ni = 0; ni < 4; ++ni)
                        acc[mi][ni] = MFMA16(alv[mi], bh[ni], acc[mi][ni]);
#pragma unroll
                for (int ni = 0; ni < 4; ++ni) blv[ni] = *(const short8*)&Bl[boff[ni]];
#pragma unroll
                for (int mi = 0; mi < 4; ++mi)
#pragma unroll
                    for (int ni = 0; ni < 4; ++ni)
                        acc[mi][ni] = MFMA16(ah[mi], blv[ni], acc[mi][ni]);
            }
            __syncthreads();
        }
    }

    const int hh = n >> 2, nl = n & 3;
    const int pxbase = p0 + (w & 1) * 64 + lq * 4;
    const int x0q = pxbase & 7;
#pragma unroll
    for (int mi = 0; mi < 4; ++mi) {
        int px = pxbase + mi * 16;
        int y = px >> 3;
#pragma unroll
        for (int ni = 0; ni < 4; ++ni) {
            int co = co0 + (w >> 1) * 64 + ni * 16 + lm;
            int nn = nl * 8 + (co >> 6);
            int dd = (co & 63) * 8 + (y >> 2);
            int t0 = hh * 32 + (y & 3) * 8 + x0q;
            if (split) {
                short4v hv, lv;
#pragma unroll
                for (int r = 0; r < 4; ++r) {
                    float xv = acc[mi][ni][r];
                    unsigned short hb = f2bf(xv);
                    hv[r] = (short)hb;
                    lv[r] = (short)f2bf(xv - bf2f(hb));
                }
                int base = (nn * 512 + dd) * 256 + t0;
                *(short4v*)&Oh[base] = hv;
                *(short4v*)&Ol[base] = lv;
            } else {
#pragma unroll
                for (int r = 0; r < 4; ++r)
                    Vt[(nn * 256 + t0 + r) * 512 + dd] = f2bf(acc[mi][ni][r]);
            }
        }
    }
}

// ---- scores: Sc[nn][q][k'] fp32 via split-bf16 16x16 MFMA (K=256) ----
// UNCHANGED from round 5.
__global__ __launch_bounds__(256) void k_scores_mfma(
        const unsigned short* __restrict__ Qh, const unsigned short* __restrict__ Ql,
        const unsigned short* __restrict__ Kh, const unsigned short* __restrict__ Kl,
        float* __restrict__ Sc) {
    __shared__ __align__(16) short Ah[4096], Al[4096], Bh[4096], Bl[4096];
    const int tid = threadIdx.x;
    const int w = tid >> 6, l = tid & 63;
    const int q0 = blockIdx.x * 128, k0 = blockIdx.y * 128, nn = blockIdx.z;
    const int lm = l & 15, lq = l >> 4;

    int arow[2], brow[2];
#pragma unroll
    for (int i = 0; i < 2; ++i) {
        int rr = w * 32 + i * 16 + (l >> 2);
        int c  = (l & 3) ^ ((rr >> 1) & 3);
        arow[i] = (nn * 512 + q0 + rr) * 256 + c * 8;
        brow[i] = (nn * 512 + k0 + rr) * 256 + c * 8;
    }
    const int lds0 = w * 2048, lds1 = w * 2048 + 1024;

    int aoff[4], boff[4];
#pragma unroll
    for (int mi = 0; mi < 4; ++mi) {
        int row = (w & 1) * 64 + mi * 16 + lm;
        aoff[mi] = row * 32 + (lq ^ ((row >> 1) & 3)) * 8;
    }
#pragma unroll
    for (int ni = 0; ni < 4; ++ni) {
        int row = (w >> 1) * 64 + ni * 16 + lm;
        boff[ni] = row * 32 + (lq ^ ((row >> 1) & 3)) * 8;
    }

    f32x4 acc[4][4];
#pragma unroll
    for (int mi = 0; mi < 4; ++mi)
#pragma unroll
        for (int ni = 0; ni < 4; ++ni) acc[mi][ni] = (f32x4){0.f, 0.f, 0.f, 0.f};

    for (int t0 = 0; t0 < 256; t0 += 32) {
        gl_lds16(Qh + arow[0] + t0, (char*)Ah + lds0);
        gl_lds16(Qh + arow[1] + t0, (char*)Ah + lds1);
        gl_lds16(Ql + arow[0] + t0, (char*)Al + lds0);
        gl_lds16(Ql + arow[1] + t0, (char*)Al + lds1);
        gl_lds16(Kh + brow[0] + t0, (char*)Bh + lds0);
        gl_lds16(Kh + brow[1] + t0, (char*)Bh + lds1);
        gl_lds16(Kl + brow[0] + t0, (char*)Bl + lds0);
        gl_lds16(Kl + brow[1] + t0, (char*)Bl + lds1);
        __syncthreads();
        short8 ah[4], bh[4];
#pragma unroll
        for (int mi = 0; mi < 4; ++mi) ah[mi] = *(const short8*)&Ah[aoff[mi]];
#pragma unroll
        for (int ni = 0; ni < 4; ++ni) bh[ni] = *(const short8*)&Bh[boff[ni]];
#pragma unroll
        for (int mi = 0; mi < 4; ++mi)
#pragma unroll
            for (int ni = 0; ni < 4; ++ni)
                acc[mi][ni] = MFMA16(ah[mi], bh[ni], acc[mi][ni]);
        {
            short8 alv[4], blv[4];
#pragma unroll
            for (int mi = 0; mi < 4; ++mi) alv[mi] = *(const short8*)&Al[aoff[mi]];
#pragma unroll
            for (int mi = 0; mi < 4; ++mi)
#pragma unroll
                for (int ni = 0; ni < 4; ++ni)
                    acc[mi][ni] = MFMA16(alv[mi], bh[ni], acc[mi][ni]);
#pragma unroll
            for (int ni = 0; ni < 4; ++ni) blv[ni] = *(const short8*)&Bl[boff[ni]];
#pragma unroll
            for (int mi = 0; mi < 4; ++mi)
#pragma unroll
                for (int ni = 0; ni < 4; ++ni)
                    acc[mi][ni] = MFMA16(ah[mi], blv[ni], acc[mi][ni]);
        }
        __syncthreads();
    }

    float* C = Sc + nn * 262144;
#pragma unroll
    for (int mi = 0; mi < 4; ++mi) {
        int qb = q0 + (w & 1) * 64 + lq * 4 + mi * 16;
#pragma unroll
        for (int ni = 0; ni < 4; ++ni) {
            int col = k0 + (w >> 1) * 64 + ni * 16 + lm;
#pragma unroll
            for (int r = 0; r < 4; ++r)
                C[(qb + r) * 512 + col] = acc[mi][ni][r];
        }
    }
}

// ---- softmax rows of 512 (+ zero Sp halo buffer while we're here) ----
// UNCHANGED from round 5.
__global__ __launch_bounds__(256) void k_softmax(float* __restrict__ Sc,
                                                 unsigned short* __restrict__ Ph,
                                                 unsigned int* __restrict__ Spz) {
    unsigned zi = blockIdx.x * 256 + threadIdx.x;
    if (zi < 2641920u) Spz[zi] = 0u;           // 5,283,840 shorts of Sp
    __shared__ float red[8];
    float* p = Sc + (size_t)blockIdx.x * 512;
    unsigned short* ph = Ph + (size_t)blockIdx.x * 512;
    const int tid = threadIdx.x;
    float x0 = p[tid], x1 = p[tid + 256];
    float m = fmaxf(x0, x1);
#pragma unroll
    for (int off = 32; off; off >>= 1) m = fmaxf(m, __shfl_xor(m, off));
    if ((tid & 63) == 0) red[tid >> 6] = m;
    __syncthreads();
    m = fmaxf(fmaxf(red[0], red[1]), fmaxf(red[2], red[3]));
    float e0 = __expf(x0 - m), e1 = __expf(x1 - m);
    float s = e0 + e1;
#pragma unroll
    for (int off = 32; off; off >>= 1) s += __shfl_xor(s, off);
    if ((tid & 63) == 0) red[4 + (tid >> 6)] = s;
    __syncthreads();
    s = red[4] + red[5] + red[6] + red[7];
    float inv = 1.0f / s;
    float p0 = e0 * inv, p1 = e1 * inv;
    p[tid] = p0;
    p[tid + 256] = p1;
    ph[tid] = f2bf(p0);
    ph[tid + 256] = f2bf(p1);
}

// ---- PV: P @ V, 16x16 bf16 MFMA, BK=64; epilogue scatters into padded Sp ----
__global__ __launch_bounds__(256) void k_pv_mfma(
        const unsigned short* __restrict__ Ph, const unsigned short* __restrict__ Vt,
        unsigned short* __restrict__ Sp) {
    __shared__ __align__(16) short Ah[8192], Bh[4096];   // [128][64], [64][64]
    const int tid = threadIdx.x;
    const int w = tid >> 6, l = tid & 63;
    const int q0 = blockIdx.x * 128, t0 = blockIdx.y * 64, nn = blockIdx.z;
    const int lm = l & 15, lq = l >> 4;
    const int r8 = l >> 3, c8 = (l & 7) ^ (l >> 3);      // stage lane mapping

    int arow[4], brow[2];
#pragma unroll
    for (int j = 0; j < 4; ++j)
        arow[j] = (nn * 512 + q0 + w * 32 + j * 8 + r8) * 512 + c8 * 8;
#pragma unroll
    for (int j = 0; j < 2; ++j)
        brow[j] = (nn * 256 + t0 + w * 16 + j * 8 + r8) * 512 + c8 * 8;
    const int ldsA = w * 4096, ldsB = w * 2048;          // bytes

    int aoff[4][2], boff[2][2];
#pragma unroll
    for (int mi = 0; mi < 4; ++mi) {
        int row = (w & 1) * 64 + mi * 16 + lm;
#pragma unroll
        for (int ks = 0; ks < 2; ++ks)
            aoff[mi][ks] = row * 64 + (((ks << 2) | lq) ^ (lm & 7)) * 8;
    }
#pragma unroll
    for (int ni = 0; ni < 2; ++ni) {
        int row = (w >> 1) * 32 + ni * 16 + lm;
#pragma unroll
        for (int ks = 0; ks < 2; ++ks)
            boff[ni][ks] = row * 64 + (((ks << 2) | lq) ^ (lm & 7)) * 8;
    }

    f32x4 acc[4][2];
#pragma unroll
    for (int mi = 0; mi < 4; ++mi)
#pragma unroll
        for (int ni = 0; ni < 2; ++ni) acc[mi][ni] = (f32x4){0.f, 0.f, 0.f, 0.f};

    for (int kc = 0; kc < 512; kc += 64) {
#pragma unroll
        for (int j = 0; j < 4; ++j)
            gl_lds16(Ph + arow[j] + kc, (char*)Ah + ldsA + j * 1024);
#pragma unroll
        for (int j = 0; j < 2; ++j)
            gl_lds16(Vt + brow[j] + kc, (char*)Bh + ldsB + j * 1024);
        __syncthreads();
#pragma unroll
        for (int ks = 0; ks < 2; ++ks) {
            short8 a[4], b[2];
#pragma unroll
            for (int mi = 0; mi < 4; ++mi) a[mi] = *(const short8*)&Ah[aoff[mi][ks]];
#pragma unroll
            for (int ni = 0; ni < 2; ++ni) b[ni] = *(const short8*)&Bh[boff[ni][ks]];
#pragma unroll
            for (int mi = 0; mi < 4; ++mi)
#pragma unroll
                for (int ni = 0; ni < 2; ++ni)
                    acc[mi][ni] = MFMA16(a[mi], b[ni], acc[mi][ni]);
        }
        __syncthreads();
    }

    // scatter into Sp[b2][yy][xx][d2]:  b2=nn>>3, s2=nn&7,
    //   ww=(qp>>4)*8+((qp>>1)&7), d2=(qp&1)*256+(t&31)*8+(t>>5)
    const int b2 = nn >> 3, s2 = nn & 7;
#pragma unroll
    for (int mi = 0; mi < 4; ++mi) {
        int qb = q0 + (w & 1) * 64 + lq * 4 + mi * 16;
#pragma unroll
        for (int ni = 0; ni < 2; ++ni) {
            int tc = t0 + (w >> 1) * 32 + ni * 16 + lm;
            int d2base = (tc & 31) * 8 + (tc >> 5);
#pragma unroll
            for (int r = 0; r < 4; ++r) {
                int qp = qb + r;
                int ww = (qp >> 4) * 8 + ((qp >> 1) & 7);
                int d2 = (qp & 1) * 256 + d2base;
                Sp[((b2 * 10 + s2 + 1) * 258 + ww + 1) * 512 + d2] =
                    f2bf(acc[mi][ni][r]);
            }
        }
    }
}

// ---- output conv (16x16), BM=128 BN=64, BK=64 -> Y NCHW fp32 ----
__global__ __launch_bounds__(256) void k_conv_o_mfma(
        const unsigned short* __restrict__ Sp, const unsigned short* __restrict__ Wh,
        const float* __restrict__ bias, float* __restrict__ Y) {
    __shared__ __align__(16) short Ah[8192], Bh[4096];   // [128][64], [64][64]
    const int tid = threadIdx.x;
    const int w = tid >> 6, l = tid & 63;
    const int n   = blockIdx.x >> 4;
    const int yy  = (blockIdx.x >> 1) & 7;
    const int x0  = (blockIdx.x & 1) * 128;
    const int co0 = blockIdx.y * 64;
    const int lm = l & 15, lq = l >> 4;
    const int r8 = l >> 3, c8 = (l & 7) ^ (l >> 3);      // stage lane mapping

    int arow[4], brow[2];
#pragma unroll
    for (int j = 0; j < 4; ++j)
        arow[j] = ((n * 10 + yy + 1) * 258 + (x0 + w * 32 + j * 8 + r8 + 1)) * 512
                  + c8 * 8;
#pragma unroll
    for (int j = 0; j < 2; ++j)
        brow[j] = (co0 + w * 16 + j * 8 + r8) * 4608 + c8 * 8;
    const int ldsA = w * 4096, ldsB = w * 2048;          // bytes

    int aoff[4][2], boff[2][2];
#pragma unroll
    for (int mi = 0; mi < 4; ++mi) {
        int row = (w & 1) * 64 + mi * 16 + lm;
#pragma unroll
        for (int ks = 0; ks < 2; ++ks)
            aoff[mi][ks] = row * 64 + (((ks << 2) | lq) ^ (lm & 7)) * 8;
    }
#pragma unroll
    for (int ni = 0; ni < 2; ++ni) {
        int row = (w >> 1) * 32 + ni * 16 + lm;
#pragma unroll
        for (int ks = 0; ks < 2; ++ks)
            boff[ni][ks] = row * 64 + (((ks << 2) | lq) ^ (lm & 7)) * 8;
    }

    f32x4 acc[4][2];
#pragma unroll
    for (int ni = 0; ni < 2; ++ni) {
        float b = bias[co0 + (w >> 1) * 32 + ni * 16 + lm];
#pragma unroll
        for (int mi = 0; mi < 4; ++mi) acc[mi][ni] = (f32x4){b, b, b, b};
    }

    for (int tap = 0; tap < 9; ++tap) {
        const int tapoff = ((tap / 3 - 1) * 258 + (tap % 3 - 1)) * 512;
        const int wb = tap * 512;
        for (int ci0 = 0; ci0 < 512; ci0 += 64) {
#pragma unroll
            for (int j = 0; j < 4; ++j)
                gl_lds16(Sp + arow[j] + tapoff + ci0, (char*)Ah + ldsA + j * 1024);
#pragma unroll
            for (int j = 0; j < 2; ++j)
                gl_lds16(Wh + brow[j] + wb + ci0, (char*)Bh + ldsB + j * 1024);
            __syncthreads();
#pragma unroll
            for (int ks = 0; ks < 2; ++ks) {
                short8 a[4], b[2];
#pragma unroll
                for (int mi = 0; mi < 4; ++mi)
                    a[mi] = *(const short8*)&Ah[aoff[mi][ks]];
#pragma unroll
                for (int ni = 0; ni < 2; ++ni)
                    b[ni] = *(const short8*)&Bh[boff[ni][ks]];
#pragma unroll
                for (int mi = 0; mi < 4; ++mi)
#pragma unroll
                    for (int ni = 0; ni < 2; ++ni)
                        acc[mi][ni] = MFMA16(a[mi], b[ni], acc[mi][ni]);
            }
            __syncthreads();
        }
    }

#pragma unroll
    for (int mi = 0; mi < 4; ++mi) {
        int px = x0 + (w & 1) * 64 + lq * 4 + mi * 16;
#pragma unroll
        for (int ni = 0; ni < 2; ++ni) {
            int co = co0 + (w >> 1) * 32 + ni * 16 + lm;
            *(f32x4*)&Y[n * 1048576 + co * 2048 + yy * 256 + px] = acc[mi][ni];
        }
    }
}

// ---------------------------------------------------------------------------
extern "C" void kernel_launch(void* const* d_in, const int* in_sizes, int n_in,
                              void* d_out, int out_size, void* d_ws, size_t ws_size,
                              hipStream_t stream) {
    const float* q  = (const float*)d_in[0];
    const float* k  = (const float*)d_in[1];
    const float* v  = (const float*)d_in[2];
    const float* Wq = (const float*)d_in[3];
    const float* bq = (const float*)d_in[4];
    const float* Wk = (const float*)d_in[5];
    const float* bk = (const float*)d_in[6];
    const float* Wv = (const float*)d_in[7];
    const float* bv = (const float*)d_in[8];
    const float* Wo = (const float*)d_in[9];
    const float* bo = (const float*)d_in[10];

    // ---- workspace layout (shorts); total 40,697,856 shorts = 81.4 MB ----
    unsigned short* W0  = (unsigned short*)d_ws;
    unsigned short* Wqh = W0;                   // 2359296 each
    unsigned short* Wql = W0 + 2359296;
    unsigned short* Wkh = W0 + 4718592;
    unsigned short* Wkl = W0 + 7077888;
    unsigned short* Wvh = W0 + 9437184;
    unsigned short* Woh = W0 + 11796480;
    unsigned short* Xvh = W0 + 14155776;        // 5570560
    unsigned short* Qh  = W0 + 19726336;        // 4194304 each
    unsigned short* Ql  = W0 + 23920640;
    unsigned short* Kh  = W0 + 28114944;
    unsigned short* Kl  = W0 + 32309248;
    unsigned short* Vt  = W0 + 36503552;
    // reuses (lifetimes): Ph over Wqh..Wkl-part (dead after conv; Woh intact);
    //                     Sp over Ql+Kh (dead after scores)
    unsigned short* Ph = W0;                    // 8388608 shorts
    unsigned short* Sp = W0 + 23920640;         // 5283840 shorts

    // ---- d_out scratch before final writes ----
    float* y_out = (float*)d_out;               // 4194304 floats (written last)
    float* attn  = y_out + 4194304;             // 8388608 floats (written by scores)
    unsigned short* Xqh = (unsigned short*)d_out;
    unsigned short* Xql = (unsigned short*)attn;
    unsigned short* Xkh = Xql + 5570560;
    unsigned short* Xkl = Xkh + 5570560;

    k_zero_halo<<<3360, 256, 0, stream>>>(Xqh, Xql, Xkh, Xkl, Xvh);
    k_prep_w<<<2048, 256, 0, stream>>>(Wq, Wk, Wv, Wo,
                                       Wqh, Wql, Wkh, Wkl, Wvh, Woh);
    k_prep_x<<<1536, 256, 0, stream>>>(q, k, v, Xqh, Xql, Xkh, Xkl, Xvh);
    k_conv_qkv_all<<<dim3(64, 4, 3), 256, 0, stream>>>(
        Xqh, Xql, Xkh, Xkl, Xvh, Wqh, Wql, Wkh, Wkl, Wvh,
        bq, bk, bv, Qh, Ql, Kh, Kl, Vt);
    k_scores_mfma<<<dim3(4, 4, 32), 256, 0, stream>>>(Qh, Ql, Kh, Kl, attn);
    k_softmax<<<16384, 256, 0, stream>>>(attn, Ph, (unsigned int*)Sp);
    k_pv_mfma<<<dim3(4, 4, 32), 256, 0, stream>>>(Ph, Vt, Sp);
    k_conv_o_mfma<<<dim3(64, 8), 256, 0, stream>>>(Sp, Woh, bo, y_out);
}

// Round 2
// 512.866 us; speedup vs baseline: 1.1398x; 1.0244x over previous
//
#include <hip/hip_runtime.h>

// ---------------------------------------------------------------------------
// MultiHeadAttention_60000693125780 — round 7
//  = round 6's conv_qkv (structural ceiling: 49% MfmaUtil = 51% of 2075TF
//    issue bound for the 2-barrier schedule) + s_setprio(1) around its MFMA
//    cluster (T5: 3 co-resident blocks at independent phases = attn-like
//    regime where setprio measured +4-7%; lockstep GEMM was null).
//  + scores BK=64 (64KB LDS, 2/CU exact), pv BK=128 (48KB), conv_o BK=128
//    (48KB): halves vmcnt(0)-drain+barrier counts in the drain-dominated
//    small-K kernels. K-accumulation order preserved -> bit-identical.
//  + fused prep (prep_x | prep_w | zero_halo by block range): -2 launches,
//    overlaps weight compute with input HBM streaming.
//  absmax tripwire: must stay exactly 0.03125.
// Layouts: Qh/Ql,Kh/Kl [nn][dd][t] bf16 hi/lo; Vt [nn][t][dd] bf16;
//          Ph [nn][q][k'] bf16; Sp padded NHWC bf16 [4][10][258][512]
// Pitch-64 swizzle (128B rows): stage lane l -> row l>>3, chunk (l&7)^(l>>3);
//   reader chunk = (ks*4+lq)^(row&7)  -> 2-way bank alias (free, m136).
// Pitch-128 swizzle (256B rows): stage lane l -> row l>>4, chunk
//   (l&15)^(row&15); reader chunk = (ks*4+lq)^(row&15) -> 2-way (free).
// ---------------------------------------------------------------------------

typedef __attribute__((ext_vector_type(8))) short short8;
typedef __attribute__((ext_vector_type(4))) float f32x4;
typedef __attribute__((ext_vector_type(4))) short short4v;

#define MFMA16(a, b, c) __builtin_amdgcn_mfma_f32_16x16x32_bf16((a), (b), (c), 0, 0, 0)

__device__ __forceinline__ void gl_lds16(const void* g, void* l) {
    __builtin_amdgcn_global_load_lds(
        (const __attribute__((address_space(1))) unsigned int*)g,
        (__attribute__((address_space(3))) unsigned int*)l, 16, 0, 0);
}
__device__ __forceinline__ unsigned short f2bf(float f) {
    unsigned u = __float_as_uint(f);
    return (unsigned short)((u + 0x7fffu + ((u >> 16) & 1u)) >> 16);
}
__device__ __forceinline__ float bf2f(unsigned short h) {
    return __uint_as_float(((unsigned)h) << 16);
}
__device__ __forceinline__ unsigned int pack_hl(float f) {
    unsigned short h = f2bf(f);
    unsigned short lo = f2bf(f - bf2f(h));
    return (unsigned)h | ((unsigned)lo << 16);
}

// ---- fused prep: [0,1536) input transpose | [1536,3584) weights | rest halo
__global__ __launch_bounds__(256) void k_prep_fused(
        const float* __restrict__ q, const float* __restrict__ k,
        const float* __restrict__ v,
        const float* __restrict__ Wq, const float* __restrict__ Wk,
        const float* __restrict__ Wv, const float* __restrict__ Wo,
        unsigned short* __restrict__ Wqh, unsigned short* __restrict__ Wql,
        unsigned short* __restrict__ Wkh, unsigned short* __restrict__ Wkl,
        unsigned short* __restrict__ Wvh, unsigned short* __restrict__ Woh,
        unsigned short* __restrict__ Xqh, unsigned short* __restrict__ Xql,
        unsigned short* __restrict__ Xkh, unsigned short* __restrict__ Xkl,
        unsigned short* __restrict__ Xvh) {
    __shared__ __align__(16) unsigned int U[8192];
    const int b = blockIdx.x;
    const int tid = threadIdx.x;
    if (b < 1536) {
        // ---- input prep: NCHW fp32 -> padded NHWC bf16 hi(/lo) ----
        const int cig = b & 15, n = (b >> 4) & 31, z = b >> 9;
        const float* X = z == 0 ? q : z == 1 ? k : v;
        unsigned short* Xh = z == 0 ? Xqh : z == 1 ? Xkh : Xvh;
        unsigned short* Xl = z == 0 ? Xql : z == 1 ? Xkl : nullptr;
#pragma unroll
        for (int it = 0; it < 8; ++it) {
            int ci_l = it * 4 + (tid >> 6);
            int pos = (tid & 63) * 4;
            const float4 rd =
                *(const float4*)&X[(size_t)(n * 512 + cig * 32 + ci_l) * 256 + pos];
            uint4 u;
            u.x = pack_hl(rd.x);
            u.y = pack_hl(rd.y);
            u.z = pack_hl(rd.z);
            u.w = pack_hl(rd.w);
            *(uint4*)&U[ci_l * 256 + pos] = u;
        }
        __syncthreads();
#pragma unroll
        for (int it = 0; it < 4; ++it) {
            int pos = it * 64 + (tid >> 2);
            int ci8 = (tid & 3) * 8;
            short8 h8, l8;
#pragma unroll
            for (int j = 0; j < 8; ++j) {
                unsigned int u = U[(ci8 + j) * 256 + pos];
                h8[j] = (short)(u & 0xffffu);
                l8[j] = (short)(u >> 16);
            }
            int yy = (pos >> 3) + 1, xx = (pos & 7) + 1;
            size_t o = (size_t)((n * 34 + yy) * 10 + xx) * 512 + cig * 32 + ci8;
            *(short8*)&Xh[o] = h8;
            if (Xl) *(short8*)&Xl[o] = l8;
        }
    } else if (b < 3584) {
        // ---- weight prep: [co][ci][tap] fp32 -> [co][tap][ci] bf16 ----
        const int bl = b - 1536;
        const int co = bl & 511, z = bl >> 9;
        const float* W = z == 0 ? Wq : z == 1 ? Wk : z == 2 ? Wv : Wo;
        unsigned short* Wh = z == 0 ? Wqh : z == 1 ? Wkh : z == 2 ? Wvh : Woh;
        unsigned short* Wl = z == 0 ? Wql : z == 1 ? Wkl : nullptr;
        const float* Wc = W + co * 4608;
#pragma unroll
        for (int it = 0; it < 9; ++it) {
            int p = it * 256 + tid;
            float2 rd = *(const float2*)&Wc[p * 2];
            int e0 = p * 2;
            int ci0 = e0 / 9, t0 = e0 - ci0 * 9;
            U[t0 * 512 + ci0] = pack_hl(rd.x);
            int e1 = e0 + 1;
            int ci1 = e1 / 9, t1 = e1 - ci1 * 9;
            U[t1 * 512 + ci1] = pack_hl(rd.y);
        }
        __syncthreads();
        unsigned short* Whc = Wh + co * 4608;
        unsigned short* Wlc = Wl ? Wl + co * 4608 : nullptr;
#pragma unroll
        for (int it = 0; it < 18; ++it) {
            int j = it * 256 + tid;
            unsigned int u = U[j];
            Whc[j] = (unsigned short)(u & 0xffffu);
            if (Wlc) Wlc[j] = (unsigned short)(u >> 16);
        }
    } else {
        // ---- halo zeroing: 84 halo cells per (array, n) ----
        const int w = tid >> 6, l = tid & 63;
        int job = (b - 3584) * 4 + w;        // 13440 jobs = 5 arrays * 32 n * 84
        int a = job / 2688;
        int r = job - a * 2688;
        int n = r / 84;
        int ii = r - n * 84;
        unsigned short* arr = a == 0 ? Xqh : a == 1 ? Xql : a == 2 ? Xkh
                                     : a == 3 ? Xkl : Xvh;
        int cell;
        if (ii < 11)      cell = ii;
        else if (ii < 73) { int j = ii - 11; cell = 19 + (j >> 1) * 10 + (j & 1); }
        else              cell = 329 + (ii - 73);
        short8 z8 = {0, 0, 0, 0, 0, 0, 0, 0};
        *(short8*)&arr[(size_t)(n * 340 + cell) * 512 + l * 8] = z8;
    }
}

// ---- merged QKV conv (16x16): z=0 Q(split), z=1 K(split), z=2 V(->Vt) ----
// round 6 structure + s_setprio around the MFMA cluster (T5 experiment).
__global__ __launch_bounds__(256) void k_conv_qkv_all(
        const unsigned short* __restrict__ Xqh, const unsigned short* __restrict__ Xql,
        const unsigned short* __restrict__ Xkh, const unsigned short* __restrict__ Xkl,
        const unsigned short* __restrict__ Xvh,
        const unsigned short* __restrict__ Wqh_, const unsigned short* __restrict__ Wql_,
        const unsigned short* __restrict__ Wkh_, const unsigned short* __restrict__ Wkl_,
        const unsigned short* __restrict__ Wvh_,
        const float* __restrict__ bq, const float* __restrict__ bk,
        const float* __restrict__ bv,
        unsigned short* __restrict__ Qh, unsigned short* __restrict__ Ql,
        unsigned short* __restrict__ Kh, unsigned short* __restrict__ Kl,
        unsigned short* __restrict__ Vt) {
    __shared__ __align__(16) short Ah[4096], Al[4096], Bh[4096], Bl[4096];
    const int z = blockIdx.z;
    const bool split = (z < 2);
    const unsigned short* Xh = z == 0 ? Xqh : z == 1 ? Xkh : Xvh;
    const unsigned short* Xl = z == 0 ? Xql : Xkl;
    const unsigned short* Wh = z == 0 ? Wqh_ : z == 1 ? Wkh_ : Wvh_;
    const unsigned short* Wl = z == 0 ? Wql_ : Wkl_;
    const float* bias = z == 0 ? bq : z == 1 ? bk : bv;
    unsigned short* Oh = z == 0 ? Qh : Kh;
    unsigned short* Ol = z == 0 ? Ql : Kl;

    const int tid = threadIdx.x;
    const int w = tid >> 6, l = tid & 63;
    const int n   = blockIdx.x >> 1;
    const int p0  = (blockIdx.x & 1) * 128;
    const int co0 = blockIdx.y * 128;
    const int lm = l & 15, lq = l >> 4;

    int arow[2], brow[2];
#pragma unroll
    for (int i = 0; i < 2; ++i) {
        int rr = w * 32 + i * 16 + (l >> 2);
        int c  = (l & 3) ^ ((rr >> 1) & 3);             // XOR bank swizzle
        int px = p0 + rr;
        int y = px >> 3, x = px & 7;
        arow[i] = ((n * 34 + y + 1) * 10 + (x + 1)) * 512 + c * 8;
        brow[i] = (co0 + rr) * 4608 + c * 8;
    }
    const int lds0 = w * 2048, lds1 = w * 2048 + 1024;

    int aoff[4], boff[4];
#pragma unroll
    for (int mi = 0; mi < 4; ++mi) {
        int row = (w & 1) * 64 + mi * 16 + lm;
        aoff[mi] = row * 32 + (lq ^ ((row >> 1) & 3)) * 8;
    }
#pragma unroll
    for (int ni = 0; ni < 4; ++ni) {
        int row = (w >> 1) * 64 + ni * 16 + lm;
        boff[ni] = row * 32 + (lq ^ ((row >> 1) & 3)) * 8;
    }

    f32x4 acc[4][4];
#pragma unroll
    for (int ni = 0; ni < 4; ++ni) {
        float b = bias[co0 + (w >> 1) * 64 + ni * 16 + lm];
#pragma unroll
        for (int mi = 0; mi < 4; ++mi) acc[mi][ni] = (f32x4){b, b, b, b};
    }

    for (int tap = 0; tap < 9; ++tap) {
        const int tapoff = ((tap / 3 - 1) * 10 + (tap % 3 - 1)) * 512;
        const int wb = tap * 512;
        for (int ci0 = 0; ci0 < 512; ci0 += 32) {
            int a0 = arow[0] + tapoff + ci0, a1 = arow[1] + tapoff + ci0;
            int b0 = brow[0] + wb + ci0,     b1 = brow[1] + wb + ci0;
            gl_lds16(Xh + a0, (char*)Ah + lds0);
            gl_lds16(Xh + a1, (char*)Ah + lds1);
            gl_lds16(Wh + b0, (char*)Bh + lds0);
            gl_lds16(Wh + b1, (char*)Bh + lds1);
            if (split) {
                gl_lds16(Xl + a0, (char*)Al + lds0);
                gl_lds16(Xl + a1, (char*)Al + lds1);
                gl_lds16(Wl + b0, (char*)Bl + lds0);
                gl_lds16(Wl + b1, (char*)Bl + lds1);
            }
            __syncthreads();
            __builtin_amdgcn_s_setprio(1);
            short8 ah[4], bh[4];
#pragma unroll
            for (int mi = 0; mi < 4; ++mi) ah[mi] = *(const short8*)&Ah[aoff[mi]];
#pragma unroll
            for (int ni = 0; ni < 4; ++ni) bh[ni] = *(const short8*)&Bh[boff[ni]];
#pragma unroll
            for (int mi = 0; mi < 4; ++mi)
#pragma unroll
                for (int ni = 0; ni < 4; ++ni)
                    acc[mi][ni] = MFMA16(ah[mi], bh[ni], acc[mi][ni]);
            if (split) {
                short8 alv[4], blv[4];
#pragma unroll
                for (int mi = 0; mi < 4; ++mi) alv[mi] = *(const short8*)&Al[aoff[mi]];
#pragma unroll
                for (int mi = 0; mi < 4; ++mi)
#pragma unroll
                    for (int ni = 0; ni < 4; ++ni)
                        acc[mi][ni] = MFMA16(alv[mi], bh[ni], acc[mi][ni]);
#pragma unroll
                for (int ni = 0; ni < 4; ++ni) blv[ni] = *(const short8*)&Bl[boff[ni]];
#pragma unroll
                for (int mi = 0; mi < 4; ++mi)
#pragma unroll
                    for (int ni = 0; ni < 4; ++ni)
                        acc[mi][ni] = MFMA16(ah[mi], blv[ni], acc[mi][ni]);
            }
            __builtin_amdgcn_s_setprio(0);
            __syncthreads();
        }
    }

    const int hh = n >> 2, nl = n & 3;
    const int pxbase = p0 + (w & 1) * 64 + lq * 4;
    const int x0q = pxbase & 7;
#pragma unroll
    for (int mi = 0; mi < 4; ++mi) {
        int px = pxbase + mi * 16;
        int y = px >> 3;
#pragma unroll
        for (int ni = 0; ni < 4; ++ni) {
            int co = co0 + (w >> 1) * 64 + ni * 16 + lm;
            int nn = nl * 8 + (co >> 6);
            int dd = (co & 63) * 8 + (y >> 2);
            int t0 = hh * 32 + (y & 3) * 8 + x0q;
            if (split) {
                short4v hv, lv;
#pragma unroll
                for (int r = 0; r < 4; ++r) {
                    float xv = acc[mi][ni][r];
                    unsigned short hb = f2bf(xv);
                    hv[r] = (short)hb;
                    lv[r] = (short)f2bf(xv - bf2f(hb));
                }
                int base = (nn * 512 + dd) * 256 + t0;
                *(short4v*)&Oh[base] = hv;
                *(short4v*)&Ol[base] = lv;
            } else {
#pragma unroll
                for (int r = 0; r < 4; ++r)
                    Vt[(nn * 256 + t0 + r) * 512 + dd] = f2bf(acc[mi][ni][r]);
            }
        }
    }
}

// ---- scores: Sc[nn][q][k'] fp32, split-bf16 16x16 MFMA, BK=64 ----
__global__ __launch_bounds__(256) void k_scores_mfma(
        const unsigned short* __restrict__ Qh, const unsigned short* __restrict__ Ql,
        const unsigned short* __restrict__ Kh, const unsigned short* __restrict__ Kl,
        float* __restrict__ Sc) {
    __shared__ __align__(16) short Ah[8192], Al[8192], Bh[8192], Bl[8192]; // 64KB
    const int tid = threadIdx.x;
    const int w = tid >> 6, l = tid & 63;
    const int q0 = blockIdx.x * 128, k0 = blockIdx.y * 128, nn = blockIdx.z;
    const int lm = l & 15, lq = l >> 4;
    const int r8 = l >> 3, c8 = (l & 7) ^ (l >> 3);

    int arow[4], brow[4];
#pragma unroll
    for (int j = 0; j < 4; ++j) {
        int rr = w * 32 + j * 8 + r8;
        arow[j] = (nn * 512 + q0 + rr) * 256 + c8 * 8;
        brow[j] = (nn * 512 + k0 + rr) * 256 + c8 * 8;
    }
    const int ldsW = w * 4096;       // bytes: wave's 32 rows x 128B

    int aoff[4][2], boff[4][2];
#pragma unroll
    for (int mi = 0; mi < 4; ++mi) {
        int row = (w & 1) * 64 + mi * 16 + lm;
#pragma unroll
        for (int ks = 0; ks < 2; ++ks)
            aoff[mi][ks] = row * 64 + ((((ks << 2) | lq) ^ (row & 7)) * 8);
    }
#pragma unroll
    for (int ni = 0; ni < 4; ++ni) {
        int row = (w >> 1) * 64 + ni * 16 + lm;
#pragma unroll
        for (int ks = 0; ks < 2; ++ks)
            boff[ni][ks] = row * 64 + ((((ks << 2) | lq) ^ (row & 7)) * 8);
    }

    f32x4 acc[4][4];
#pragma unroll
    for (int mi = 0; mi < 4; ++mi)
#pragma unroll
        for (int ni = 0; ni < 4; ++ni) acc[mi][ni] = (f32x4){0.f, 0.f, 0.f, 0.f};

    for (int t0 = 0; t0 < 256; t0 += 64) {
#pragma unroll
        for (int j = 0; j < 4; ++j)
            gl_lds16(Qh + arow[j] + t0, (char*)Ah + ldsW + j * 1024);
#pragma unroll
        for (int j = 0; j < 4; ++j)
            gl_lds16(Ql + arow[j] + t0, (char*)Al + ldsW + j * 1024);
#pragma unroll
        for (int j = 0; j < 4; ++j)
            gl_lds16(Kh + brow[j] + t0, (char*)Bh + ldsW + j * 1024);
#pragma unroll
        for (int j = 0; j < 4; ++j)
            gl_lds16(Kl + brow[j] + t0, (char*)Bl + ldsW + j * 1024);
        __syncthreads();
#pragma unroll
        for (int ks = 0; ks < 2; ++ks) {
            short8 ah[4], bh[4];
#pragma unroll
            for (int mi = 0; mi < 4; ++mi) ah[mi] = *(const short8*)&Ah[aoff[mi][ks]];
#pragma unroll
            for (int ni = 0; ni < 4; ++ni) bh[ni] = *(const short8*)&Bh[boff[ni][ks]];
#pragma unroll
            for (int mi = 0; mi < 4; ++mi)
#pragma unroll
                for (int ni = 0; ni < 4; ++ni)
                    acc[mi][ni] = MFMA16(ah[mi], bh[ni], acc[mi][ni]);
            short8 alv[4], blv[4];
#pragma unroll
            for (int mi = 0; mi < 4; ++mi) alv[mi] = *(const short8*)&Al[aoff[mi][ks]];
#pragma unroll
            for (int mi = 0; mi < 4; ++mi)
#pragma unroll
                for (int ni = 0; ni < 4; ++ni)
                    acc[mi][ni] = MFMA16(alv[mi], bh[ni], acc[mi][ni]);
#pragma unroll
            for (int ni = 0; ni < 4; ++ni) blv[ni] = *(const short8*)&Bl[boff[ni][ks]];
#pragma unroll
            for (int mi = 0; mi < 4; ++mi)
#pragma unroll
                for (int ni = 0; ni < 4; ++ni)
                    acc[mi][ni] = MFMA16(ah[mi], blv[ni], acc[mi][ni]);
        }
        __syncthreads();
    }

    float* C = Sc + nn * 262144;
#pragma unroll
    for (int mi = 0; mi < 4; ++mi) {
        int qb = q0 + (w & 1) * 64 + lq * 4 + mi * 16;
#pragma unroll
        for (int ni = 0; ni < 4; ++ni) {
            int col = k0 + (w >> 1) * 64 + ni * 16 + lm;
#pragma unroll
            for (int r = 0; r < 4; ++r)
                C[(qb + r) * 512 + col] = acc[mi][ni][r];
        }
    }
}

// ---- softmax rows of 512 (+ zero Sp halo buffer) — unchanged ----
__global__ __launch_bounds__(256) void k_softmax(float* __restrict__ Sc,
                                                 unsigned short* __restrict__ Ph,
                                                 unsigned int* __restrict__ Spz) {
    unsigned zi = blockIdx.x * 256 + threadIdx.x;
    if (zi < 2641920u) Spz[zi] = 0u;           // 5,283,840 shorts of Sp
    __shared__ float red[8];
    float* p = Sc + (size_t)blockIdx.x * 512;
    unsigned short* ph = Ph + (size_t)blockIdx.x * 512;
    const int tid = threadIdx.x;
    float x0 = p[tid], x1 = p[tid + 256];
    float m = fmaxf(x0, x1);
#pragma unroll
    for (int off = 32; off; off >>= 1) m = fmaxf(m, __shfl_xor(m, off));
    if ((tid & 63) == 0) red[tid >> 6] = m;
    __syncthreads();
    m = fmaxf(fmaxf(red[0], red[1]), fmaxf(red[2], red[3]));
    float e0 = __expf(x0 - m), e1 = __expf(x1 - m);
    float s = e0 + e1;
#pragma unroll
    for (int off = 32; off; off >>= 1) s += __shfl_xor(s, off);
    if ((tid & 63) == 0) red[4 + (tid >> 6)] = s;
    __syncthreads();
    s = red[4] + red[5] + red[6] + red[7];
    float inv = 1.0f / s;
    float p0 = e0 * inv, p1 = e1 * inv;
    p[tid] = p0;
    p[tid + 256] = p1;
    ph[tid] = f2bf(p0);
    ph[tid + 256] = f2bf(p1);
}

// ---- PV: P @ V, 16x16 bf16 MFMA, BK=128; scatters into padded Sp ----
__global__ __launch_bounds__(256) void k_pv_mfma(
        const unsigned short* __restrict__ Ph, const unsigned short* __restrict__ Vt,
        unsigned short* __restrict__ Sp) {
    __shared__ __align__(16) short Ah[16384], Bh[8192];  // [128][128], [64][128]
    const int tid = threadIdx.x;
    const int w = tid >> 6, l = tid & 63;
    const int q0 = blockIdx.x * 128, t0 = blockIdx.y * 64, nn = blockIdx.z;
    const int lm = l & 15, lq = l >> 4;
    const int r4 = l >> 4, c16 = l & 15;                 // pitch-128 stage map

    int arow[8], brow[4];
#pragma unroll
    for (int j = 0; j < 8; ++j) {
        int rt = w * 32 + j * 4 + r4;
        arow[j] = (nn * 512 + q0 + rt) * 512 + ((c16 ^ (rt & 15)) * 8);
    }
#pragma unroll
    for (int j = 0; j < 4; ++j) {
        int rt = w * 16 + j * 4 + r4;
        brow[j] = (nn * 256 + t0 + rt) * 512 + ((c16 ^ (rt & 15)) * 8);
    }
    const int ldsA = w * 8192, ldsB = w * 4096;          // bytes

    int aoff[4][4], boff[2][4];
#pragma unroll
    for (int mi = 0; mi < 4; ++mi) {
        int row = (w & 1) * 64 + mi * 16 + lm;
#pragma unroll
        for (int ks = 0; ks < 4; ++ks)
            aoff[mi][ks] = row * 128 + ((((ks << 2) | lq) ^ (row & 15)) * 8);
    }
#pragma unroll
    for (int ni = 0; ni < 2; ++ni) {
        int row = (w >> 1) * 32 + ni * 16 + lm;
#pragma unroll
        for (int ks = 0; ks < 4; ++ks)
            boff[ni][ks] = row * 128 + ((((ks << 2) | lq) ^ (row & 15)) * 8);
    }

    f32x4 acc[4][2];
#pragma unroll
    for (int mi = 0; mi < 4; ++mi)
#pragma unroll
        for (int ni = 0; ni < 2; ++ni) acc[mi][ni] = (f32x4){0.f, 0.f, 0.f, 0.f};

    for (int kc = 0; kc < 512; kc += 128) {
#pragma unroll
        for (int j = 0; j < 8; ++j)
            gl_lds16(Ph + arow[j] + kc, (char*)Ah + ldsA + j * 1024);
#pragma unroll
        for (int j = 0; j < 4; ++j)
            gl_lds16(Vt + brow[j] + kc, (char*)Bh + ldsB + j * 1024);
        __syncthreads();
#pragma unroll
        for (int ks = 0; ks < 4; ++ks) {
            short8 a[4], b[2];
#pragma unroll
            for (int mi = 0; mi < 4; ++mi) a[mi] = *(const short8*)&Ah[aoff[mi][ks]];
#pragma unroll
            for (int ni = 0; ni < 2; ++ni) b[ni] = *(const short8*)&Bh[boff[ni][ks]];
#pragma unroll
            for (int mi = 0; mi < 4; ++mi)
#pragma unroll
                for (int ni = 0; ni < 2; ++ni)
                    acc[mi][ni] = MFMA16(a[mi], b[ni], acc[mi][ni]);
        }
        __syncthreads();
    }

    // scatter into Sp[b2][yy][xx][d2]:  b2=nn>>3, s2=nn&7,
    //   ww=(qp>>4)*8+((qp>>1)&7), d2=(qp&1)*256+(t&31)*8+(t>>5)
    const int b2 = nn >> 3, s2 = nn & 7;
#pragma unroll
    for (int mi = 0; mi < 4; ++mi) {
        int qb = q0 + (w & 1) * 64 + lq * 4 + mi * 16;
#pragma unroll
        for (int ni = 0; ni < 2; ++ni) {
            int tc = t0 + (w >> 1) * 32 + ni * 16 + lm;
            int d2base = (tc & 31) * 8 + (tc >> 5);
#pragma unroll
            for (int r = 0; r < 4; ++r) {
                int qp = qb + r;
                int ww = (qp >> 4) * 8 + ((qp >> 1) & 7);
                int d2 = (qp & 1) * 256 + d2base;
                Sp[((b2 * 10 + s2 + 1) * 258 + ww + 1) * 512 + d2] =
                    f2bf(acc[mi][ni][r]);
            }
        }
    }
}

// ---- output conv (16x16), BM=128 BN=64, BK=128 -> Y NCHW fp32 ----
__global__ __launch_bounds__(256) void k_conv_o_mfma(
        const unsigned short* __restrict__ Sp, const unsigned short* __restrict__ Wh,
        const float* __restrict__ bias, float* __restrict__ Y) {
    __shared__ __align__(16) short Ah[16384], Bh[8192];  // [128][128], [64][128]
    const int tid = threadIdx.x;
    const int w = tid >> 6, l = tid & 63;
    const int n   = blockIdx.x >> 4;
    const int yy  = (blockIdx.x >> 1) & 7;
    const int x0  = (blockIdx.x & 1) * 128;
    const int co0 = blockIdx.y * 64;
    const int lm = l & 15, lq = l >> 4;
    const int r4 = l >> 4, c16 = l & 15;                 // pitch-128 stage map

    int arow[8], brow[4];
#pragma unroll
    for (int j = 0; j < 8; ++j) {
        int rt = w * 32 + j * 4 + r4;
        arow[j] = ((n * 10 + yy + 1) * 258 + (x0 + rt + 1)) * 512
                  + ((c16 ^ (rt & 15)) * 8);
    }
#pragma unroll
    for (int j = 0; j < 4; ++j) {
        int rt = w * 16 + j * 4 + r4;
        brow[j] = (co0 + rt) * 4608 + ((c16 ^ (rt & 15)) * 8);
    }
    const int ldsA = w * 8192, ldsB = w * 4096;          // bytes

    int aoff[4][4], boff[2][4];
#pragma unroll
    for (int mi = 0; mi < 4; ++mi) {
        int row = (w & 1) * 64 + mi * 16 + lm;
#pragma unroll
        for (int ks = 0; ks < 4; ++ks)
            aoff[mi][ks] = row * 128 + ((((ks << 2) | lq) ^ (row & 15)) * 8);
    }
#pragma unroll
    for (int ni = 0; ni < 2; ++ni) {
        int row = (w >> 1) * 32 + ni * 16 + lm;
#pragma unroll
        for (int ks = 0; ks < 4; ++ks)
            boff[ni][ks] = row * 128 + ((((ks << 2) | lq) ^ (row & 15)) * 8);
    }

    f32x4 acc[4][2];
#pragma unroll
    for (int ni = 0; ni < 2; ++ni) {
        float b = bias[co0 + (w >> 1) * 32 + ni * 16 + lm];
#pragma unroll
        for (int mi = 0; mi < 4; ++mi) acc[mi][ni] = (f32x4){b, b, b, b};
    }

    for (int tap = 0; tap < 9; ++tap) {
        const int tapoff = ((tap / 3 - 1) * 258 + (tap % 3 - 1)) * 512;
        const int wb = tap * 512;
        for (int ci0 = 0; ci0 < 512; ci0 += 128) {
#pragma unroll
            for (int j = 0; j < 8; ++j)
                gl_lds16(Sp + arow[j] + tapoff + ci0, (char*)Ah + ldsA + j * 1024);
#pragma unroll
            for (int j = 0; j < 4; ++j)
                gl_lds16(Wh + brow[j] + wb + ci0, (char*)Bh + ldsB + j * 1024);
            __syncthreads();
#pragma unroll
            for (int ks = 0; ks < 4; ++ks) {
                short8 a[4], b[2];
#pragma unroll
                for (int mi = 0; mi < 4; ++mi)
                    a[mi] = *(const short8*)&Ah[aoff[mi][ks]];
#pragma unroll
                for (int ni = 0; ni < 2; ++ni)
                    b[ni] = *(const short8*)&Bh[boff[ni][ks]];
#pragma unroll
                for (int mi = 0; mi < 4; ++mi)
#pragma unroll
                    for (int ni = 0; ni < 2; ++ni)
                        acc[mi][ni] = MFMA16(a[mi], b[ni], acc[mi][ni]);
            }
            __syncthreads();
        }
    }

#pragma unroll
    for (int mi = 0; mi < 4; ++mi) {
        int px = x0 + (w & 1) * 64 + lq * 4 + mi * 16;
#pragma unroll
        for (int ni = 0; ni < 2; ++ni) {
            int co = co0 + (w >> 1) * 32 + ni * 16 + lm;
            *(f32x4*)&Y[n * 1048576 + co * 2048 + yy * 256 + px] = acc[mi][ni];
        }
    }
}

// ---------------------------------------------------------------------------
extern "C" void kernel_launch(void* const* d_in, const int* in_sizes, int n_in,
                              void* d_out, int out_size, void* d_ws, size_t ws_size,
                              hipStream_t stream) {
    const float* q  = (const float*)d_in[0];
    const float* k  = (const float*)d_in[1];
    const float* v  = (const float*)d_in[2];
    const float* Wq = (const float*)d_in[3];
    const float* bq = (const float*)d_in[4];
    const float* Wk = (const float*)d_in[5];
    const float* bk = (const float*)d_in[6];
    const float* Wv = (const float*)d_in[7];
    const float* bv = (const float*)d_in[8];
    const float* Wo = (const float*)d_in[9];
    const float* bo = (const float*)d_in[10];

    // ---- workspace layout (shorts); total 40,697,856 shorts = 81.4 MB ----
    unsigned short* W0  = (unsigned short*)d_ws;
    unsigned short* Wqh = W0;                   // 2359296 each
    unsigned short* Wql = W0 + 2359296;
    unsigned short* Wkh = W0 + 4718592;
    unsigned short* Wkl = W0 + 7077888;
    unsigned short* Wvh = W0 + 9437184;
    unsigned short* Woh = W0 + 11796480;
    unsigned short* Xvh = W0 + 14155776;        // 5570560
    unsigned short* Qh  = W0 + 19726336;        // 4194304 each
    unsigned short* Ql  = W0 + 23920640;
    unsigned short* Kh  = W0 + 28114944;
    unsigned short* Kl  = W0 + 32309248;
    unsigned short* Vt  = W0 + 36503552;
    // reuses (lifetimes): Ph over Wqh..Wkl-part (dead after conv; Woh intact);
    //                     Sp over Ql+Kh (dead after scores)
    unsigned short* Ph = W0;                    // 8388608 shorts
    unsigned short* Sp = W0 + 23920640;         // 5283840 shorts

    // ---- d_out scratch before final writes ----
    float* y_out = (float*)d_out;               // 4194304 floats (written last)
    float* attn  = y_out + 4194304;             // 8388608 floats (written by scores)
    unsigned short* Xqh = (unsigned short*)d_out;
    unsigned short* Xql = (unsigned short*)attn;
    unsigned short* Xkh = Xql + 5570560;
    unsigned short* Xkl = Xkh + 5570560;

    k_prep_fused<<<6944, 256, 0, stream>>>(q, k, v, Wq, Wk, Wv, Wo,
                                           Wqh, Wql, Wkh, Wkl, Wvh, Woh,
                                           Xqh, Xql, Xkh, Xkl, Xvh);
    k_conv_qkv_all<<<dim3(64, 4, 3), 256, 0, stream>>>(
        Xqh, Xql, Xkh, Xkl, Xvh, Wqh, Wql, Wkh, Wkl, Wvh,
        bq, bk, bv, Qh, Ql, Kh, Kl, Vt);
    k_scores_mfma<<<dim3(4, 4, 32), 256, 0, stream>>>(Qh, Ql, Kh, Kl, attn);
    k_softmax<<<16384, 256, 0, stream>>>(attn, Ph, (unsigned int*)Sp);
    k_pv_mfma<<<dim3(4, 4, 32), 256, 0, stream>>>(Ph, Vt, Sp);
    k_conv_o_mfma<<<dim3(64, 8), 256, 0, stream>>>(Sp, Woh, bo, y_out);
}